// Round 1
// baseline (54.910 us; speedup 1.0000x reference)
//
#include <hip/hip_runtime.h>
#include <math.h>

#define NB 8192
#define NH 4096
#define TPB 256

__device__ __forceinline__ int sgn(float x) { return (x > 0.f) - (x < 0.f); }

// One block per row. Computes Sp, Spp, St, Stt, Spt and directional match
// count M for the row, then writes 3 floats to ws:
//   ws[3*row+0] = sum((p-t)^2) = Spp - 2*Spt + Stt
//   ws[3*row+1] = M (match count over H-1 diffs)
//   ws[3*row+2] = (1 - corr_row) / 2
__global__ __launch_bounds__(TPB) void row_stats_kernel(
    const float* __restrict__ pred, const float* __restrict__ targ,
    float* __restrict__ ws)
{
    const int row = blockIdx.x;
    const float* p = pred + (size_t)row * NH;
    const float* t = targ + (size_t)row * NH;
    const int tid = threadIdx.x;

    float Sp = 0.f, Spp = 0.f, St = 0.f, Stt = 0.f, Spt = 0.f;
    int M = 0;

    const float4* p4 = (const float4*)p;
    const float4* t4 = (const float4*)t;

#pragma unroll
    for (int it = 0; it < (NH / 4) / TPB; ++it) {
        const int q = it * TPB + tid;
        const float4 pv = p4[q];
        const float4 tv = t4[q];

        Sp  += (pv.x + pv.y) + (pv.z + pv.w);
        St  += (tv.x + tv.y) + (tv.z + tv.w);
        Spp += (pv.x * pv.x + pv.y * pv.y) + (pv.z * pv.z + pv.w * pv.w);
        Stt += (tv.x * tv.x + tv.y * tv.y) + (tv.z * tv.z + tv.w * tv.w);
        Spt += (pv.x * tv.x + pv.y * tv.y) + (pv.z * tv.z + pv.w * tv.w);

        // Directional diffs: j = 4q (needs element 4q-1), 4q+1, 4q+2, 4q+3.
        if (q > 0) {
            const float pprev = p[4 * q - 1];   // L1/L2-resident
            const float tprev = t[4 * q - 1];
            const int sp0 = sgn(pv.x - pprev), st0 = sgn(tv.x - tprev);
            M += (st0 == 0) | (sp0 == st0);
        }
        {
            const int s1p = sgn(pv.y - pv.x), s1t = sgn(tv.y - tv.x);
            M += (s1t == 0) | (s1p == s1t);
            const int s2p = sgn(pv.z - pv.y), s2t = sgn(tv.z - tv.y);
            M += (s2t == 0) | (s2p == s2t);
            const int s3p = sgn(pv.w - pv.z), s3t = sgn(tv.w - tv.z);
            M += (s3t == 0) | (s3p == s3t);
        }
    }

    // 64-lane wave reduce.
    float fM = (float)M;   // per-wave M <= 4*4*64 = 1024, exact in fp32
#pragma unroll
    for (int off = 32; off > 0; off >>= 1) {
        Sp  += __shfl_down(Sp, off);
        Spp += __shfl_down(Spp, off);
        St  += __shfl_down(St, off);
        Stt += __shfl_down(Stt, off);
        Spt += __shfl_down(Spt, off);
        fM  += __shfl_down(fM, off);
    }

    __shared__ float red[4][6];
    const int wave = tid >> 6;
    const int lane = tid & 63;
    if (lane == 0) {
        red[wave][0] = Sp;  red[wave][1] = Spp; red[wave][2] = St;
        red[wave][3] = Stt; red[wave][4] = Spt; red[wave][5] = fM;
    }
    __syncthreads();
    if (tid == 0) {
        Sp  = (red[0][0] + red[1][0]) + (red[2][0] + red[3][0]);
        Spp = (red[0][1] + red[1][1]) + (red[2][1] + red[3][1]);
        St  = (red[0][2] + red[1][2]) + (red[2][2] + red[3][2]);
        Stt = (red[0][3] + red[1][3]) + (red[2][3] + red[3][3]);
        Spt = (red[0][4] + red[1][4]) + (red[2][4] + red[3][4]);
        fM  = (red[0][5] + red[1][5]) + (red[2][5] + red[3][5]);

        const float invH = 1.0f / NH;
        const float mp = Sp * invH;
        const float mt = St * invH;
        const float varp = (Spp - Sp * Sp * invH) * (1.0f / (NH - 1));
        const float vart = (Stt - St * St * invH) * (1.0f / (NH - 1));
        const float sdp = sqrtf(fmaxf(varp, 0.f)) + 1e-6f;
        const float sdt = sqrtf(fmaxf(vart, 0.f)) + 1e-6f;
        const float cov = Spt * invH - mp * mt;
        const float corr = cov / (sdp * sdt);

        ws[row * 3 + 0] = (Spp - 2.f * Spt) + Stt;
        ws[row * 3 + 1] = fM;
        ws[row * 3 + 2] = (1.f - corr) * 0.5f;
    }
}

__global__ __launch_bounds__(TPB) void final_reduce_kernel(
    const float* __restrict__ ws, float* __restrict__ out)
{
    const int tid = threadIdx.x;
    double s_mse = 0.0, s_match = 0.0, s_corr = 0.0;
    for (int i = tid; i < NB; i += TPB) {
        s_mse   += (double)ws[3 * i + 0];
        s_match += (double)ws[3 * i + 1];
        s_corr  += (double)ws[3 * i + 2];
    }
#pragma unroll
    for (int off = 32; off > 0; off >>= 1) {
        s_mse   += __shfl_down(s_mse, off);
        s_match += __shfl_down(s_match, off);
        s_corr  += __shfl_down(s_corr, off);
    }
    __shared__ double red[4][3];
    const int wave = tid >> 6;
    const int lane = tid & 63;
    if (lane == 0) {
        red[wave][0] = s_mse; red[wave][1] = s_match; red[wave][2] = s_corr;
    }
    __syncthreads();
    if (tid == 0) {
        s_mse   = (red[0][0] + red[1][0]) + (red[2][0] + red[3][0]);
        s_match = (red[0][1] + red[1][1]) + (red[2][1] + red[3][1]);
        s_corr  = (red[0][2] + red[1][2]) + (red[2][2] + red[3][2]);

        const double mse       = s_mse / ((double)NB * (double)NH);
        const double dir_loss  = 1.0 - s_match / ((double)NB * (double)(NH - 1));
        const double corr_loss = s_corr / (double)NB;
        out[0] = (float)(0.5 * mse + 0.25 * (dir_loss + corr_loss));
    }
}

extern "C" void kernel_launch(void* const* d_in, const int* in_sizes, int n_in,
                              void* d_out, int out_size, void* d_ws, size_t ws_size,
                              hipStream_t stream) {
    const float* pred = (const float*)d_in[0];
    const float* targ = (const float*)d_in[1];
    float* ws  = (float*)d_ws;   // needs 8192*3*4 = 96 KB
    float* out = (float*)d_out;

    row_stats_kernel<<<NB, TPB, 0, stream>>>(pred, targ, ws);
    final_reduce_kernel<<<1, TPB, 0, stream>>>(ws, out);
}